// Round 2
// baseline (593.909 us; speedup 1.0000x reference)
//
#include <hip/hip_runtime.h>
#include <hip/hip_bf16.h>
#include <stdint.h>
#include <stddef.h>

typedef __hip_bfloat16 bf16;
typedef __attribute__((ext_vector_type(8))) __bf16 bf16x8;
typedef __attribute__((ext_vector_type(4))) float f32x4;

__device__ __forceinline__ bf16 f2b(float x) { return __float2bfloat16(x); }

// async global->LDS copy, 16B per lane. LDS dest must be wave-uniform base + lane*16.
__device__ __forceinline__ void async_copy16(const bf16* g, bf16* l) {
    __builtin_amdgcn_global_load_lds(
        (const __attribute__((address_space(1))) unsigned int*)g,
        (__attribute__((address_space(3))) unsigned int*)l,
        16, 0, 0);
}

// ---------------------------------------------------------------- utility kernels
__global__ void zero_kernel(float* __restrict__ p, int n) {
    int i = blockIdx.x * blockDim.x + threadIdx.x;
    if (i < n) p[i] = 0.f;
}

// W1T[n*320 + p]: padded-triplet layout. p = t*32 + q; q<30 -> W1[(t*30+q)*1024 + n], else 0.
__global__ void transpose_w1_pad32(const float* __restrict__ W1, bf16* __restrict__ WT) {
    int idx = blockIdx.x * blockDim.x + threadIdx.x;
    if (idx >= 1024 * 320) return;
    int n = idx / 320;
    int p = idx - n * 320;
    int t = p >> 5;
    int q = p & 31;
    float v = (q < 30) ? W1[(size_t)(t * 30 + q) * 1024 + n] : 0.f;
    WT[idx] = f2b(v);
}

// Tiled transpose+cast for W2: WT[n*Kpad+k] = bf16(W[k*N+n]). 64x64 tiles via LDS.
__global__ __launch_bounds__(256)
void transpose_pad_tiled(const float* __restrict__ W, bf16* __restrict__ WT,
                         int K, int N, int Kpad) {
    __shared__ bf16 tile[64][65];
    const int t = threadIdx.x;
    const int tk = blockIdx.x * 64;
    const int tn = blockIdx.y * 64;
    #pragma unroll
    for (int r = 0; r < 16; ++r) {
        int kl = (t >> 6) + r * 4;
        int nl = t & 63;
        int k = tk + kl, n = tn + nl;
        float v = (k < K) ? W[(size_t)k * N + n] : 0.f;
        tile[kl][nl] = f2b(v);
    }
    __syncthreads();
    #pragma unroll
    for (int r = 0; r < 16; ++r) {
        int nl = (t >> 6) + r * 4;
        int kl = t & 63;
        WT[(size_t)(tn + nl) * Kpad + tk + kl] = tile[kl][nl];
    }
}

// ---------------------------------------------------------------- feature kernel (r8 winner)
__global__ __launch_bounds__(256)
void feat_kernel(const float* __restrict__ S, const float* __restrict__ E,
                 bf16* __restrict__ feat) {
    __shared__ bf16 sF[128 * 320];
    const int tid = threadIdx.x;
    const size_t r0 = (size_t)blockIdx.x * 128;
    const int row = tid >> 1, tp = tid & 1;

    #pragma unroll
    for (int c = 0; c < 5; ++c) {
        int t = c * 2 + tp;
        const float* sp = S + (r0 + row) * 30 + t * 3;
        float fi = sp[0], fj = sp[1], d = sp[2];
        int ii = (int)fi;
        int jj = (int)fj;
        bf16 f[32];
        #pragma unroll
        for (int q = 0; q < 10; ++q) f[q]      = f2b((ii != 0) ? E[ii * 10 + q] : 0.f);
        #pragma unroll
        for (int q = 0; q < 10; ++q) f[10 + q] = f2b((jj != 0) ? E[jj * 10 + q] : 0.f);
        #pragma unroll
        for (int q = 0; q < 10; ++q) {
            float df = (float)(q + 1) * 0.7f - d;
            f[20 + q] = f2b((ii != 0) ? __expf(-df * df) : 0.f);   // GAMMA = 1
        }
        f[30] = f2b(0.f);
        f[31] = f2b(0.f);
        #pragma unroll
        for (int j = 0; j < 4; ++j) {
            int c0 = t * 4 + j;
            *(bf16x8*)&sF[row * 320 + ((c0 ^ (row & 7)) << 3)] = *(const bf16x8*)&f[j * 8];
        }
    }
    __syncthreads();
    #pragma unroll
    for (int i = 0; i < 20; ++i) {
        int c2 = i * 256 + tid;        // 0..5119
        int r  = c2 / 40;
        int c  = c2 - r * 40;
        int p  = c ^ (r & 7);
        *(bf16x8*)(feat + r0 * 320 + (size_t)c2 * 8) = *(const bf16x8*)&sF[r * 320 + p * 8];
    }
}

// ---------------------------------------------------------------- 256x256 8-phase MFMA GEMM
// Same 8-phase schedule as r1, with the drain-defeat fix: the four independently
// guarded LDS regions are now four DISTINCT __shared__ objects (sA0,sA1,sB0,sB1).
// LLVM's waitcnt pass tracks global_load_lds (LDS-DMA) per underlying object; with
// one object per region it can emit counted vmcnt before each phase's ds_reads
// instead of the conservative vmcnt(0) that a single sA[2] array forces (r1: that
// hidden drain made 8-phase == 2-phase, MfmaUtil 38%).
//
// Phase map per steady iteration (K-tiles 2t -> {sA0,sB0}, 2t+1 -> {sA1,sB1}):
//   P1: read sA0/sB0  stage A(2t+1)h0->sA1     P5: read sA1/sB1  stage A(2t+2)h0->sA0
//   P2: read sA0      stage A(2t+1)h1->sA1     P6: read sA1      stage A(2t+2)h1->sA0
//   P3: read sA0/sB0                           P7: read sA1/sB1
//   P4: read sA0      stage B(2t+2)->sB0,      P8: read sA1      stage B(2t+3)->sB1,
//       vmcnt(4)                                   vmcnt(4)
// vmcnt ledger (4 loads = one B tile or two A halves): entry {B(2t+1)}=4; P1/P2 -> 8;
// P4 -> 12, vmcnt(4) retires B(2t+1)+A(2t+1) (P5-P8 reads safe); P5/P6 -> 8; P8 -> 12,
// vmcnt(4) retires B(2t+2)+A(2t+2) (next P1 reads safe); leaves {B(2t+3)}=4 invariant.
// Region-death: a stage's dest region was last ds_read one full phase earlier, and any
// wave issuing the stage has passed that phase's closing barrier, which every wave only
// crosses after its own lgkmcnt(0) -> all reads of the region have landed. Race-free.
// Last iteration is peeled ("flex"): runtime guards + vmcnt(0) fallbacks; odd KTILES
// gets a 4-phase tail on buf0, fully drained by flex-P8's vmcnt(0).
#define BARRIER() __builtin_amdgcn_s_barrier()
#define WAITV4()  asm volatile("s_waitcnt vmcnt(4)" ::: "memory")
#define WAITV0()  asm volatile("s_waitcnt vmcnt(0)" ::: "memory")
#define WAITL0()  asm volatile("s_waitcnt lgkmcnt(0)" ::: "memory")

#define LDA4(arr, s2, mih)                                                      \
    {                                                                           \
        _Pragma("unroll") for (int m_ = 0; m_ < 4; ++m_) {                      \
            int rr_ = wr * 128 + ((mih) * 4 + m_) * 16 + l16;                   \
            av[m_] = *(const bf16x8*)&arr[rr_ * 64 +                            \
                     ((((s2) * 4 + quad) ^ (rr_ & 7)) << 3)];                   \
        }                                                                       \
    }
#define LDB4(arr, s2)                                                           \
    {                                                                           \
        _Pragma("unroll") for (int n_ = 0; n_ < 4; ++n_) {                      \
            int rr_ = wc * 64 + n_ * 16 + l16;                                  \
            bv[n_] = *(const bf16x8*)&arr[rr_ * 64 +                            \
                     ((((s2) * 4 + quad) ^ (rr_ & 7)) << 3)];                   \
        }                                                                       \
    }
#define MFMA16(mih)                                                             \
    {                                                                           \
        __builtin_amdgcn_s_setprio(1);                                          \
        _Pragma("unroll") for (int m_ = 0; m_ < 4; ++m_)                        \
            _Pragma("unroll") for (int n_ = 0; n_ < 4; ++n_)                    \
                acc[(mih) * 4 + m_][n_] =                                       \
                    __builtin_amdgcn_mfma_f32_16x16x32_bf16(                    \
                        av[m_], bv[n_], acc[(mih) * 4 + m_][n_], 0, 0, 0);      \
        __builtin_amdgcn_s_setprio(0);                                          \
    }
#define STAGE_A2(arr, kt, h)                                                    \
    {                                                                           \
        _Pragma("unroll") for (int i_ = (h) * 2; i_ < (h) * 2 + 2; ++i_)        \
            async_copy16(gA[i_] + (kt) * 64, &arr[(i_ * 512 + tid) * 8]);       \
    }
#define STAGE_B4(arr, kt)                                                       \
    {                                                                           \
        _Pragma("unroll") for (int i_ = 0; i_ < 4; ++i_)                        \
            async_copy16(gB[i_] + (kt) * 64, &arr[(i_ * 512 + tid) * 8]);       \
    }

template <int EPI, int KTILES>
__global__ __launch_bounds__(512, 2)
void gemm8p(const bf16* __restrict__ A, const bf16* __restrict__ BT,
            const float* __restrict__ bias, bf16* __restrict__ C,
            float* __restrict__ outf, const float* __restrict__ w3,
            int lda, int ldbt, int ldc, int mt) {
    __shared__ __align__(16) bf16 sA0[256 * 64];
    __shared__ __align__(16) bf16 sA1[256 * 64];
    __shared__ __align__(16) bf16 sB0[256 * 64];
    __shared__ __align__(16) bf16 sB1[256 * 64];
    const int tid  = threadIdx.x;
    const int lane = tid & 63;
    const int wave = tid >> 6;
    const int wr = wave >> 2, wc = wave & 3;
    const int l16 = lane & 15, quad = (lane >> 4) & 3;

    // bijective XCD chunking (m204): consecutive wg share one mtile -> A panel
    // fetched once per XCD L2; B (<=2MB) stays resident.
    const int nwg = mt * 4;
    const int q = nwg >> 3, r = nwg & 7;
    const int xcd = blockIdx.x & 7, idx = blockIdx.x >> 3;
    const int wg = (xcd < r) ? (xcd * (q + 1) + idx)
                             : (r * (q + 1) + (xcd - r) * q + idx);
    const int mtile = wg >> 2, ntile = wg & 3;
    const size_t m0 = (size_t)mtile * 256;
    const int    n0 = ntile * 256;

    // staging bases: pre-swizzled global source, linear LDS dest (rule: both-sides)
    const bf16* gA[4];
    const bf16* gB[4];
    #pragma unroll
    for (int i = 0; i < 4; ++i) {
        int s   = i * 512 + tid;
        int row = s >> 3;
        int kof = (((s & 7) ^ (row & 7)) << 3);
        gA[i] = A  + (m0 + (size_t)row) * lda  + kof;
        gB[i] = BT + ((size_t)(n0 + row)) * ldbt + kof;
    }

    f32x4 acc[8][4];
    #pragma unroll
    for (int i = 0; i < 8; ++i)
        #pragma unroll
        for (int j = 0; j < 4; ++j) acc[i][j] = (f32x4){0.f, 0.f, 0.f, 0.f};
    bf16x8 av[4], bv[4];

    // prologue: A0,B0 -> buf0; B1 -> buf1; leave {B1} in flight (steady invariant)
    STAGE_A2(sA0, 0, 0); STAGE_A2(sA0, 0, 1);
    STAGE_B4(sB0, 0);
    if (KTILES > 1) { STAGE_B4(sB1, 1); WAITV4(); } else { WAITV0(); }
    BARRIER();

    constexpr int NIT = KTILES / 2;
    #pragma unroll 1
    for (int t = 0; t < NIT - 1; ++t) {   // steady: all prefetch targets in range
        const int kb = 2 * t + 1, kc = 2 * t + 2, kd = 2 * t + 3;
        // P1
        LDA4(sA0, 0, 0); LDB4(sB0, 0);
        STAGE_A2(sA1, kb, 0);
        BARRIER(); WAITL0(); MFMA16(0); BARRIER();
        // P2
        LDA4(sA0, 0, 1);
        STAGE_A2(sA1, kb, 1);
        BARRIER(); WAITL0(); MFMA16(1); BARRIER();
        // P3
        LDA4(sA0, 1, 0); LDB4(sB0, 1);
        BARRIER(); WAITL0(); MFMA16(0); BARRIER();
        // P4
        LDA4(sA0, 1, 1);
        STAGE_B4(sB0, kc); WAITV4();
        BARRIER(); WAITL0(); MFMA16(1); BARRIER();
        // P5
        LDA4(sA1, 0, 0); LDB4(sB1, 0);
        STAGE_A2(sA0, kc, 0);
        BARRIER(); WAITL0(); MFMA16(0); BARRIER();
        // P6
        LDA4(sA1, 0, 1);
        STAGE_A2(sA0, kc, 1);
        BARRIER(); WAITL0(); MFMA16(1); BARRIER();
        // P7
        LDA4(sA1, 1, 0); LDB4(sB1, 1);
        BARRIER(); WAITL0(); MFMA16(0); BARRIER();
        // P8
        LDA4(sA1, 1, 1);
        STAGE_B4(sB1, kd); WAITV4();
        BARRIER(); WAITL0(); MFMA16(1); BARRIER();
    }
    if (NIT >= 1) {   // flex (peeled last even iteration): guarded prefetch
        const int t2 = NIT - 1;
        const int kb = 2 * t2 + 1, kc = 2 * t2 + 2, kd = 2 * t2 + 3;
        // P1
        LDA4(sA0, 0, 0); LDB4(sB0, 0);
        STAGE_A2(sA1, kb, 0);
        BARRIER(); WAITL0(); MFMA16(0); BARRIER();
        // P2
        LDA4(sA0, 0, 1);
        STAGE_A2(sA1, kb, 1);
        BARRIER(); WAITL0(); MFMA16(1); BARRIER();
        // P3
        LDA4(sA0, 1, 0); LDB4(sB0, 1);
        BARRIER(); WAITL0(); MFMA16(0); BARRIER();
        // P4
        LDA4(sA0, 1, 1);
        if (kc < KTILES) { STAGE_B4(sB0, kc); WAITV4(); } else { WAITV0(); }
        BARRIER(); WAITL0(); MFMA16(1); BARRIER();
        // P5
        LDA4(sA1, 0, 0); LDB4(sB1, 0);
        if (kc < KTILES) STAGE_A2(sA0, kc, 0);
        BARRIER(); WAITL0(); MFMA16(0); BARRIER();
        // P6
        LDA4(sA1, 0, 1);
        if (kc < KTILES) STAGE_A2(sA0, kc, 1);
        BARRIER(); WAITL0(); MFMA16(1); BARRIER();
        // P7
        LDA4(sA1, 1, 0); LDB4(sB1, 1);
        BARRIER(); WAITL0(); MFMA16(0); BARRIER();
        // P8
        LDA4(sA1, 1, 1);
        if (kd < KTILES) { STAGE_B4(sB1, kd); WAITV4(); } else { WAITV0(); }
        BARRIER(); WAITL0(); MFMA16(1); BARRIER();
    }
    if (KTILES & 1) {   // odd tail: K-tile KTILES-1 (even index -> buf0), fully landed
        LDA4(sA0, 0, 0); LDB4(sB0, 0); BARRIER(); WAITL0(); MFMA16(0); BARRIER();
        LDA4(sA0, 0, 1);               BARRIER(); WAITL0(); MFMA16(1); BARRIER();
        LDA4(sA0, 1, 0); LDB4(sB0, 1); BARRIER(); WAITL0(); MFMA16(0); BARRIER();
        LDA4(sA0, 1, 1);               BARRIER(); WAITL0(); MFMA16(1); BARRIER();
    }

    if (EPI == 0) {
        #pragma unroll
        for (int ni = 0; ni < 4; ++ni) {
            int col = n0 + wc * 64 + ni * 16 + l16;
            float bb = bias[col];
            #pragma unroll
            for (int mi = 0; mi < 8; ++mi) {
                #pragma unroll
                for (int rr = 0; rr < 4; ++rr) {
                    size_t row = m0 + wr * 128 + mi * 16 + quad * 4 + rr;
                    float v = acc[mi][ni][rr] + bb;
                    v = v > 0.f ? v : 0.f;
                    C[row * ldc + col] = f2b(v);
                }
            }
        }
    } else {
        float bb[4], ww[4];
        #pragma unroll
        for (int ni = 0; ni < 4; ++ni) {
            int col = n0 + wc * 64 + ni * 16 + l16;
            bb[ni] = bias[col];
            ww[ni] = w3[col];
        }
        #pragma unroll
        for (int mi = 0; mi < 8; ++mi) {
            #pragma unroll
            for (int rr = 0; rr < 4; ++rr) {
                float p = 0.f;
                #pragma unroll
                for (int ni = 0; ni < 4; ++ni) {
                    float v = acc[mi][ni][rr] + bb[ni];
                    v = v > 0.f ? v : 0.f;
                    p += v * ww[ni];
                }
                #pragma unroll
                for (int off = 1; off < 16; off <<= 1)
                    p += __shfl_xor(p, off, 64);
                if (l16 == 0) {
                    size_t row = m0 + wr * 128 + mi * 16 + quad * 4 + rr;
                    atomicAdd(&outf[row], p);
                }
            }
        }
    }
}

#undef LDA4
#undef LDB4
#undef MFMA16
#undef STAGE_A2
#undef STAGE_B4

__global__ void final_kernel(const float* __restrict__ outf, const float* __restrict__ b3,
                             float* __restrict__ out, int n) {
    int i = blockIdx.x * blockDim.x + threadIdx.x;
    if (i < n) out[i] = outf[i] + b3[0];
}

// ---------------------------------------------------------------- zero-workspace fallback
#define FB_ROWS 8
__global__ __launch_bounds__(256)
void fallback_kernel(const float* __restrict__ S, const float* __restrict__ E,
                     const float* __restrict__ W1, const float* __restrict__ b1,
                     const float* __restrict__ W2, const float* __restrict__ b2,
                     const float* __restrict__ W3, const float* __restrict__ b3,
                     float* __restrict__ out) {
    __shared__ float feat[FB_ROWS][304];
    __shared__ float X1[FB_ROWS][1024];
    __shared__ float red[256];
    const int tid = threadIdx.x;
    const size_t r0 = (size_t)blockIdx.x * FB_ROWS;

    if (tid < FB_ROWS * 10) {
        int r = tid / 10, t = tid - r * 10;
        const float* s = S + (r0 + r) * 30 + t * 3;
        float fi = s[0], fj = s[1], d = s[2];
        int ii = (int)fi;
        int jj = (int)fj;
        float* o = &feat[r][t * 30];
        #pragma unroll
        for (int c = 0; c < 10; ++c) o[c]      = (ii != 0) ? E[ii * 10 + c] : 0.f;
        #pragma unroll
        for (int c = 0; c < 10; ++c) o[10 + c] = (jj != 0) ? E[jj * 10 + c] : 0.f;
        #pragma unroll
        for (int c = 0; c < 10; ++c) {
            float df = (float)(c + 1) * 0.7f - d;
            o[20 + c] = (ii != 0) ? __expf(-df * df) : 0.f;
        }
    }
    __syncthreads();

    for (int i = 0; i < FB_ROWS * 1024 / 256; ++i) {
        int idx = i * 256 + tid;
        int r = idx & (FB_ROWS - 1);
        int c = idx >> 3;
        float a = b1[c];
        for (int k = 0; k < 300; ++k)
            a += feat[r][k] * W1[(size_t)k * 1024 + c];
        X1[r][c] = a > 0.f ? a : 0.f;
    }
    __syncthreads();

    {
        int r  = tid & (FB_ROWS - 1);
        int cg = tid >> 3;
        float acc = 0.f;
        for (int cc = 0; cc < 32; ++cc) {
            int c = cg * 32 + cc;
            float a = b2[c];
            for (int k = 0; k < 1024; ++k)
                a += X1[r][k] * W2[(size_t)k * 1024 + c];
            a = a > 0.f ? a : 0.f;
            acc += a * W3[c];
        }
        red[tid] = acc;
    }
    __syncthreads();
    if (tid < FB_ROWS) {
        float s = 0.f;
        for (int g = 0; g < 32; ++g) s += red[g * FB_ROWS + tid];
        out[r0 + tid] = s + b3[0];
    }
}

// ---------------------------------------------------------------- launch
extern "C" void kernel_launch(void* const* d_in, const int* in_sizes, int n_in,
                              void* d_out, int out_size, void* d_ws, size_t ws_size,
                              hipStream_t stream) {
    const float* S  = (const float*)d_in[0];
    const float* E  = (const float*)d_in[1];
    const float* W1 = (const float*)d_in[2];
    const float* b1 = (const float*)d_in[3];
    const float* W2 = (const float*)d_in[4];
    const float* b2 = (const float*)d_in[5];
    const float* W3 = (const float*)d_in[6];
    const float* b3 = (const float*)d_in[7];
    float* out = (float*)d_out;

    const int Bn  = out_size;   // 131072
    const int HID = 1024;
    const int K1  = 320;

    const size_t MIN_WS = 16u * 1024u * 1024u;
    if (ws_size < MIN_WS) {
        fallback_kernel<<<Bn / FB_ROWS, 256, 0, stream>>>(S, E, W1, b1, W2, b2, W3, b3, out);
        return;
    }

    char* ws = (char*)d_ws;
    size_t off = 0;
    auto take = [&](size_t bytes) { char* p = ws + off; off += (bytes + 255) & ~(size_t)255; return p; };
    float* outf = (float*)take((size_t)Bn * sizeof(float));
    bf16*  W1T  = (bf16*) take((size_t)HID * K1 * sizeof(bf16));
    bf16*  W2T  = (bf16*) take((size_t)HID * HID * sizeof(bf16));

    size_t avail   = ws_size - off - 256;
    size_t per_row = (size_t)K1 * sizeof(bf16) + (size_t)HID * sizeof(bf16); // 2688 B
    size_t chunk   = (avail / per_row) & ~(size_t)1023;   // multiple of 1024 rows (-> mt%4==0)
    if (chunk > (size_t)Bn) chunk = Bn;
    bf16* featc = (bf16*)take(chunk * K1 * sizeof(bf16));
    bf16* X1c   = (bf16*)take(chunk * HID * sizeof(bf16));

    zero_kernel<<<(Bn + 255) / 256, 256, 0, stream>>>(outf, Bn);
    transpose_w1_pad32<<<(HID * K1 + 255) / 256, 256, 0, stream>>>(W1, W1T);
    {
        dim3 g2(HID / 64, HID / 64);
        transpose_pad_tiled<<<g2, 256, 0, stream>>>(W2, W2T, HID, HID, HID);
    }

    for (size_t r0 = 0; r0 < (size_t)Bn; r0 += chunk) {
        size_t rows = ((size_t)Bn - r0 < chunk) ? ((size_t)Bn - r0) : chunk;
        int mt = (int)(rows / 256);
        feat_kernel<<<(unsigned)(rows / 128), 256, 0, stream>>>(S + r0 * 30, E, featc);
        gemm8p<0, 5><<<(unsigned)(mt * 4), 512, 0, stream>>>(
            featc, W1T, b1, X1c, nullptr, nullptr, K1, K1, HID, mt);
        gemm8p<1, 16><<<(unsigned)(mt * 4), 512, 0, stream>>>(
            X1c, W2T, b2, nullptr, outf + r0, W3, HID, HID, 0, mt);
    }
    final_kernel<<<(Bn + 255) / 256, 256, 0, stream>>>(outf, b3, out, Bn);
}

// Round 4
// 562.797 us; speedup vs baseline: 1.0553x; 1.0553x over previous
//
#include <hip/hip_runtime.h>
#include <hip/hip_bf16.h>
#include <stdint.h>
#include <stddef.h>

typedef __hip_bfloat16 bf16;
typedef __attribute__((ext_vector_type(8))) __bf16 bf16x8;
typedef __attribute__((ext_vector_type(4))) float f32x4;
typedef __attribute__((ext_vector_type(4))) unsigned int u32x4;

__device__ __forceinline__ bf16 f2b(float x) { return __float2bfloat16(x); }
__device__ __forceinline__ uint32_t b16bits(float x) {
    union { bf16 h; unsigned short u; } cv; cv.h = __float2bfloat16(x); return (uint32_t)cv.u;
}

// async global->LDS copy, 16B per lane. LDS dest must be wave-uniform base + lane*16.
__device__ __forceinline__ void async_copy16(const bf16* g, bf16* l) {
    __builtin_amdgcn_global_load_lds(
        (const __attribute__((address_space(1))) unsigned int*)g,
        (__attribute__((address_space(3))) unsigned int*)l,
        16, 0, 0);
}

// XCD-aware remap: blocks dispatch round-robin to 8 XCDs by l%8. Map each group of
// 64 consecutive l to 8 m-tiles x 8 n-tiles so the 8 blocks of one XCD share ONE
// m-tile -> A row-tile fetched once into that XCD's L2.
__device__ __forceinline__ void remap_xcd(int l, int mt, int& mtile, int& ntile) {
    int g  = l >> 6;
    int r  = l & 63;
    int gm = g << 3;
    if (gm + 8 <= mt) { mtile = gm + (r & 7); ntile = r >> 3; }
    else { int p = mt - gm; mtile = gm + (r % p); ntile = r / p; }  // tail group
}

// ---------------------------------------------------------------- utility kernels
// W1T[n*320 + p]: padded-triplet layout. p = t*32 + q; q<30 -> W1[(t*30+q)*1024 + n], else 0.
__global__ void transpose_w1_pad32(const float* __restrict__ W1, bf16* __restrict__ WT) {
    int idx = blockIdx.x * blockDim.x + threadIdx.x;
    if (idx >= 1024 * 320) return;
    int n = idx / 320;
    int p = idx - n * 320;
    int t = p >> 5;
    int q = p & 31;
    float v = (q < 30) ? W1[(size_t)(t * 30 + q) * 1024 + n] : 0.f;
    WT[idx] = f2b(v);
}

// Tiled transpose+cast for W2: WT[n*Kpad+k] = bf16(W[k*N+n]). 64x64 tiles via LDS.
__global__ __launch_bounds__(256)
void transpose_pad_tiled(const float* __restrict__ W, bf16* __restrict__ WT,
                         int K, int N, int Kpad) {
    __shared__ bf16 tile[64][65];
    const int t = threadIdx.x;
    const int tk = blockIdx.x * 64;
    const int tn = blockIdx.y * 64;
    #pragma unroll
    for (int r = 0; r < 16; ++r) {
        int kl = (t >> 6) + r * 4;
        int nl = t & 63;
        int k = tk + kl, n = tn + nl;
        float v = (k < K) ? W[(size_t)k * N + n] : 0.f;
        tile[kl][nl] = f2b(v);
    }
    __syncthreads();
    #pragma unroll
    for (int r = 0; r < 16; ++r) {
        int nl = (t >> 6) + r * 4;
        int kl = t & 63;
        WT[(size_t)(tn + nl) * Kpad + tk + kl] = tile[kl][nl];
    }
}

// ---------------------------------------------------------------- feature kernel (r8 winner)
__global__ __launch_bounds__(256)
void feat_kernel(const float* __restrict__ S, const float* __restrict__ E,
                 bf16* __restrict__ feat) {
    __shared__ bf16 sF[128 * 320];
    const int tid = threadIdx.x;
    const size_t r0 = (size_t)blockIdx.x * 128;
    const int row = tid >> 1, tp = tid & 1;

    #pragma unroll
    for (int c = 0; c < 5; ++c) {
        int t = c * 2 + tp;
        const float* sp = S + (r0 + row) * 30 + t * 3;
        float fi = sp[0], fj = sp[1], d = sp[2];
        int ii = (int)fi;
        int jj = (int)fj;
        bf16 f[32];
        #pragma unroll
        for (int q = 0; q < 10; ++q) f[q]      = f2b((ii != 0) ? E[ii * 10 + q] : 0.f);
        #pragma unroll
        for (int q = 0; q < 10; ++q) f[10 + q] = f2b((jj != 0) ? E[jj * 10 + q] : 0.f);
        #pragma unroll
        for (int q = 0; q < 10; ++q) {
            float df = (float)(q + 1) * 0.7f - d;
            f[20 + q] = f2b((ii != 0) ? __expf(-df * df) : 0.f);   // GAMMA = 1
        }
        f[30] = f2b(0.f);
        f[31] = f2b(0.f);
        #pragma unroll
        for (int j = 0; j < 4; ++j) {
            int c0 = t * 4 + j;
            *(bf16x8*)&sF[row * 320 + ((c0 ^ (row & 7)) << 3)] = *(const bf16x8*)&f[j * 8];
        }
    }
    __syncthreads();
    #pragma unroll
    for (int i = 0; i < 20; ++i) {
        int c2 = i * 256 + tid;        // 0..5119
        int r  = c2 / 40;
        int c  = c2 - r * 40;
        int p  = c ^ (r & 7);
        *(bf16x8*)(feat + r0 * 320 + (size_t)c2 * 8) = *(const bf16x8*)&sF[r * 320 + p * 8];
    }
}

// ---------------------------------------------------------------- MFMA GEMM (r0 K-loop, new epilogues)
// C[M,N] = A[M,K] @ BT[N,K]^T ; 128x128 tile, BK=64, 4 waves (2x2), 4x4 16x16x32 frags.
// K-loop identical to the verified r0 winner.
// EPI==0: C = relu(acc+bias) staged through the (dead) 32KB LDS as packed bf16
//   pairs (bank-swizzled), then stored fully coalesced (dwordx4, 256B runs).
// EPI==1: relu-dot-w3 partial per n-tile. Each row's 128 cols are split across the
//   two wc-waves -> reduce the two halves through LDS (single writer per plane/row),
//   then plane store outf[ntile*ldc + row]; final_kernel sums the 8 planes.
template <int EPI, int KTOTAL>
__global__ __launch_bounds__(256)
void gemm_kernel(const bf16* __restrict__ A, const bf16* __restrict__ BT,
                 const float* __restrict__ bias, bf16* __restrict__ C,
                 float* __restrict__ outf, const float* __restrict__ w3,
                 int lda, int ldbt, int ldc, int mt) {
    __shared__ __align__(16) bf16 sAB[2 * 128 * 64];
    bf16* sA = sAB;
    bf16* sB = sAB + 128 * 64;
    const int tid  = threadIdx.x;
    const int lane = tid & 63;
    const int wave = tid >> 6;
    const int wr = wave >> 1, wc = wave & 1;
    const int l16 = lane & 15, quad = lane >> 4;
    int mtile, ntile;
    remap_xcd(blockIdx.x, mt, mtile, ntile);
    const size_t m0 = (size_t)mtile * 128;
    const int    n0 = ntile * 128;

    // loop-invariant staging bases (kk enters as an immediate offset after unroll)
    const bf16* gA[4];
    const bf16* gB[4];
    #pragma unroll
    for (int i = 0; i < 4; ++i) {
        int s   = i * 256 + tid;
        int row = s >> 3;
        int kof = (((s & 7) ^ (row & 7)) << 3);
        gA[i] = A  + (m0 + row) * lda          + kof;
        gB[i] = BT + (size_t)(n0 + row) * ldbt + kof;
    }

    f32x4 acc[4][4];
    #pragma unroll
    for (int i = 0; i < 4; ++i)
        #pragma unroll
        for (int j = 0; j < 4; ++j) acc[i][j] = (f32x4){0.f, 0.f, 0.f, 0.f};

    #pragma unroll
    for (int kk = 0; kk < KTOTAL; kk += 64) {
        #pragma unroll
        for (int i = 0; i < 4; ++i) {
            int s = i * 256 + tid;
            async_copy16(gA[i] + kk, &sA[s * 8]);
            async_copy16(gB[i] + kk, &sB[s * 8]);
        }
        __syncthreads();
        #pragma unroll
        for (int s2 = 0; s2 < 2; ++s2) {
            int clog = s2 * 4 + quad;
            bf16x8 a[4], b[4];
            #pragma unroll
            for (int mi = 0; mi < 4; ++mi) {
                int r = wr * 64 + mi * 16 + l16;
                a[mi] = *(const bf16x8*)&sA[r * 64 + ((clog ^ (r & 7)) << 3)];
            }
            #pragma unroll
            for (int ni = 0; ni < 4; ++ni) {
                int r = wc * 64 + ni * 16 + l16;
                b[ni] = *(const bf16x8*)&sB[r * 64 + ((clog ^ (r & 7)) << 3)];
            }
            #pragma unroll
            for (int mi = 0; mi < 4; ++mi)
                #pragma unroll
                for (int ni = 0; ni < 4; ++ni)
                    acc[mi][ni] = __builtin_amdgcn_mfma_f32_16x16x32_bf16(
                        a[mi], b[ni], acc[mi][ni], 0, 0, 0);
        }
        __syncthreads();
    }

    if (EPI == 0) {
        // ---- pack relu(acc+bias) into LDS as bf16 pairs, bank-swizzled ----
        uint32_t* sCw = (uint32_t*)sAB;
        #pragma unroll
        for (int ni = 0; ni < 4; ++ni) {
            int col = n0 + wc * 64 + ni * 16 + l16;
            float bv = bias[col];
            #pragma unroll
            for (int mi = 0; mi < 4; ++mi) {
                int rowb = wr * 64 + mi * 16 + quad * 4;
                int cpb  = (wc * 64 + ni * 16 + (l16 & 14)) >> 1;
                #pragma unroll
                for (int r = 0; r < 4; ++r) {
                    float v = acc[mi][ni][r] + bv;
                    v = v > 0.f ? v : 0.f;
                    float vp = __shfl_xor(v, 1);
                    uint32_t lo = (l16 & 1) ? b16bits(vp) : b16bits(v);
                    uint32_t hi = (l16 & 1) ? b16bits(v)  : b16bits(vp);
                    uint32_t pk = lo | (hi << 16);
                    int row = rowb + r;
                    int cp  = cpb ^ (((row >> 2) & 7) << 3);
                    if ((l16 & 1) == 0) sCw[row * 64 + cp] = pk;
                }
            }
        }
        __syncthreads();
        // ---- coalesced store: 16 lanes cover one 256B row segment ----
        const int rb = tid >> 4;           // 0..15
        const int cs = tid & 15;           // 16B segment within row
        #pragma unroll
        for (int p = 0; p < 8; ++p) {
            int row = rb + p * 16;
            int cp  = (cs * 4) ^ (((row >> 2) & 7) << 3);
            u32x4 w = *(const u32x4*)&sCw[row * 64 + cp];
            *(u32x4*)(C + (m0 + row) * ldc + n0 + cs * 8) = w;
        }
    } else {
        // ---- per-wave partial (64 of the n-tile's 128 cols), LDS-reduce the two
        // wc halves, single writer per (plane,row) ----
        float* sRed = (float*)sAB;   // 256 floats
        #pragma unroll
        for (int mi = 0; mi < 4; ++mi) {
            #pragma unroll
            for (int r = 0; r < 4; ++r) {
                float p = 0.f;
                #pragma unroll
                for (int ni = 0; ni < 4; ++ni) {
                    int col = n0 + wc * 64 + ni * 16 + l16;
                    float v = acc[mi][ni][r] + bias[col];
                    v = v > 0.f ? v : 0.f;
                    p += v * w3[col];
                }
                #pragma unroll
                for (int off = 1; off < 16; off <<= 1)
                    p += __shfl_xor(p, off, 64);
                if (l16 == 0)
                    sRed[wc * 128 + wr * 64 + mi * 16 + quad * 4 + r] = p;
            }
        }
        __syncthreads();
        if (tid < 128)
            outf[(size_t)ntile * ldc + m0 + tid] = sRed[tid] + sRed[128 + tid];
    }
}

__global__ void final_kernel(const float* __restrict__ outf, const float* __restrict__ b3,
                             float* __restrict__ out, int n) {
    int i = blockIdx.x * blockDim.x + threadIdx.x;
    if (i < n) {
        float s = b3[0];
        #pragma unroll
        for (int t = 0; t < 8; ++t) s += outf[(size_t)t * n + i];
        out[i] = s;
    }
}

// ---------------------------------------------------------------- zero-workspace fallback
#define FB_ROWS 8
__global__ __launch_bounds__(256)
void fallback_kernel(const float* __restrict__ S, const float* __restrict__ E,
                     const float* __restrict__ W1, const float* __restrict__ b1,
                     const float* __restrict__ W2, const float* __restrict__ b2,
                     const float* __restrict__ W3, const float* __restrict__ b3,
                     float* __restrict__ out) {
    __shared__ float feat[FB_ROWS][304];
    __shared__ float X1[FB_ROWS][1024];
    __shared__ float red[256];
    const int tid = threadIdx.x;
    const size_t r0 = (size_t)blockIdx.x * FB_ROWS;

    if (tid < FB_ROWS * 10) {
        int r = tid / 10, t = tid - r * 10;
        const float* s = S + (r0 + r) * 30 + t * 3;
        float fi = s[0], fj = s[1], d = s[2];
        int ii = (int)fi;
        int jj = (int)fj;
        float* o = &feat[r][t * 30];
        #pragma unroll
        for (int c = 0; c < 10; ++c) o[c]      = (ii != 0) ? E[ii * 10 + c] : 0.f;
        #pragma unroll
        for (int c = 0; c < 10; ++c) o[10 + c] = (jj != 0) ? E[jj * 10 + c] : 0.f;
        #pragma unroll
        for (int c = 0; c < 10; ++c) {
            float df = (float)(c + 1) * 0.7f - d;
            o[20 + c] = (ii != 0) ? __expf(-df * df) : 0.f;
        }
    }
    __syncthreads();

    for (int i = 0; i < FB_ROWS * 1024 / 256; ++i) {
        int idx = i * 256 + tid;
        int r = idx & (FB_ROWS - 1);
        int c = idx >> 3;
        float a = b1[c];
        for (int k = 0; k < 300; ++k)
            a += feat[r][k] * W1[(size_t)k * 1024 + c];
        X1[r][c] = a > 0.f ? a : 0.f;
    }
    __syncthreads();

    {
        int r  = tid & (FB_ROWS - 1);
        int cg = tid >> 3;
        float acc = 0.f;
        for (int cc = 0; cc < 32; ++cc) {
            int c = cg * 32 + cc;
            float a = b2[c];
            for (int k = 0; k < 1024; ++k)
                a += X1[r][k] * W2[(size_t)k * 1024 + c];
            a = a > 0.f ? a : 0.f;
            acc += a * W3[c];
        }
        red[tid] = acc;
    }
    __syncthreads();
    if (tid < FB_ROWS) {
        float s = 0.f;
        for (int g = 0; g < 32; ++g) s += red[g * FB_ROWS + tid];
        out[r0 + tid] = s + b3[0];
    }
}

// ---------------------------------------------------------------- launch
extern "C" void kernel_launch(void* const* d_in, const int* in_sizes, int n_in,
                              void* d_out, int out_size, void* d_ws, size_t ws_size,
                              hipStream_t stream) {
    const float* S  = (const float*)d_in[0];
    const float* E  = (const float*)d_in[1];
    const float* W1 = (const float*)d_in[2];
    const float* b1 = (const float*)d_in[3];
    const float* W2 = (const float*)d_in[4];
    const float* b2 = (const float*)d_in[5];
    const float* W3 = (const float*)d_in[6];
    const float* b3 = (const float*)d_in[7];
    float* out = (float*)d_out;

    const int Bn  = out_size;   // 131072
    const int HID = 1024;
    const int K1  = 320;

    const size_t MIN_WS = 16u * 1024u * 1024u;
    if (ws_size < MIN_WS) {
        fallback_kernel<<<Bn / FB_ROWS, 256, 0, stream>>>(S, E, W1, b1, W2, b2, W3, b3, out);
        return;
    }

    char* ws = (char*)d_ws;
    size_t off = 0;
    auto take = [&](size_t bytes) { char* p = ws + off; off += (bytes + 255) & ~(size_t)255; return p; };
    float* outf8 = (float*)take((size_t)8 * Bn * sizeof(float));   // 8 n-tile planes
    bf16*  W1T   = (bf16*) take((size_t)HID * K1 * sizeof(bf16));
    bf16*  W2T   = (bf16*) take((size_t)HID * HID * sizeof(bf16));

    size_t avail   = ws_size - off - 256;
    size_t per_row = (size_t)K1 * sizeof(bf16) + (size_t)HID * sizeof(bf16); // 2688 B
    size_t chunk   = (avail / per_row) & ~(size_t)1023;   // multiple of 1024 rows
    if (chunk > (size_t)Bn) chunk = Bn;
    bf16* featc = (bf16*)take(chunk * K1 * sizeof(bf16));
    bf16* X1c   = (bf16*)take(chunk * HID * sizeof(bf16));

    transpose_w1_pad32<<<(HID * K1 + 255) / 256, 256, 0, stream>>>(W1, W1T);
    {
        dim3 g2(HID / 64, HID / 64);
        transpose_pad_tiled<<<g2, 256, 0, stream>>>(W2, W2T, HID, HID, HID);
    }

    for (size_t r0 = 0; r0 < (size_t)Bn; r0 += chunk) {
        size_t rows = ((size_t)Bn - r0 < chunk) ? ((size_t)Bn - r0) : chunk;
        int mt = (int)(rows / 128);
        feat_kernel<<<(unsigned)(rows / 128), 256, 0, stream>>>(S + r0 * 30, E, featc);
        gemm_kernel<0, 320><<<(unsigned)(mt * 8), 256, 0, stream>>>(
            featc, W1T, b1, X1c, nullptr, nullptr, K1, K1, HID, mt);
        // EPI=1: outf plane stride = Bn (plane base + r0 gives chunk offset within plane)
        gemm_kernel<1, 1024><<<(unsigned)(mt * 8), 256, 0, stream>>>(
            X1c, W2T, b2, nullptr, outf8 + r0, W3, HID, HID, Bn, mt);
    }
    final_kernel<<<(Bn + 255) / 256, 256, 0, stream>>>(outf8, b3, out, Bn);
}